// Round 11
// baseline (550.496 us; speedup 1.0000x reference)
//
#include <hip/hip_runtime.h>
#include <stdint.h>

#define AS1 __attribute__((address_space(1)))
#define AS3 __attribute__((address_space(3)))

typedef __bf16 bf16x8 __attribute__((ext_vector_type(8)));   // 4 VGPRs
typedef float  f32x4  __attribute__((ext_vector_type(4)));
typedef float  f32x16 __attribute__((ext_vector_type(16)));

#define MFMA16(a, b, c) __builtin_amdgcn_mfma_f32_16x16x32_bf16((a), (b), (c), 0, 0, 0)
#define MFMA32(a, b, c) __builtin_amdgcn_mfma_f32_32x32x16_bf16((a), (b), (c), 0, 0, 0)

// ---- constants for this problem ----
#define SEQ   512
#define NBAT  64
#define DM    768
#define NH    12
#define DH    64
#define NQKV  2304
#define NTOK  (NBAT * SEQ)   // 32768
#define NKB   12             // both GEMMs contract over K=768 -> 12 blocks of 64
#define GS    (NKB * 2048)   // elems per 32-row fragment group (32*768)

__device__ __forceinline__ uint16_t f2bf(float x) {          // fp32 -> bf16 RNE
  uint32_t u = __float_as_uint(x);
  return (uint16_t)((u + 0x7FFFu + ((u >> 16) & 1u)) >> 16);
}

__device__ __forceinline__ void async16(uint16_t* lds, const uint16_t* g) {
  __builtin_amdgcn_global_load_lds((AS1 void*)(uintptr_t)(const void*)g,
                                   (AS3 void*)lds, 16, 0, 0);
}

// row->column XOR swizzle: conflict-free for MFMA fragment reads (R5-verified).
__device__ __forceinline__ int swz(int r) { return (r ^ (r >> 3)) & 7; }

// B fragment-packed layout: 16B chunk ((g*NKB + kb)*4 + ks)*64 + lane holds
//   B[row = g*32 + (lane&31)][k = kb*64 + ks*16 + (lane>>5)*8 .. +8)
// -> a wave's per-(kb,ks) fragment load is 64 consecutive chunks = 1KB contiguous.

// ---------------- converter: weights + biases only (tokens fused into QKV GEMM) ----------------
__global__ __launch_bounds__(256) void k_cvt(
    const float* __restrict__ Wq, const float* __restrict__ Wk,
    const float* __restrict__ Wv, const float* __restrict__ Wo,
    const float* __restrict__ bq, const float* __restrict__ bk, const float* __restrict__ bv,
    uint16_t* __restrict__ Wqkv_pk, uint16_t* __restrict__ Wob_pk,
    float* __restrict__ bqkv) {
  int i = blockIdx.x * 256 + threadIdx.x;     // grid covers 221184 chunks
  int lane = i & 63, ks = (i >> 6) & 3, kb = (i >> 8) % NKB, g = i / 3072;
  int r32 = lane & 31, kk = kb * 64 + ks * 16 + (lane >> 5) * 8;
  {                                            // Wqkv: 2304*768/8 chunks
    int row = g * 32 + r32;
    const float* src = (row < 768)  ? Wq + (size_t)row * 768 + kk
                     : (row < 1536) ? Wk + (size_t)(row - 768) * 768 + kk
                                    : Wv + (size_t)(row - 1536) * 768 + kk;
    float4 a = *(const float4*)src, b = *(const float4*)(src + 4);
    union { uint16_t u[8]; uint4 v; } o;
    o.u[0] = f2bf(a.x); o.u[1] = f2bf(a.y); o.u[2] = f2bf(a.z); o.u[3] = f2bf(a.w);
    o.u[4] = f2bf(b.x); o.u[5] = f2bf(b.y); o.u[6] = f2bf(b.z); o.u[7] = f2bf(b.w);
    ((uint4*)Wqkv_pk)[i] = o.v;
  }
  if (i < 73728) {                             // Wo: 768*768/8 chunks
    const float* src = Wo + (size_t)(g * 32 + r32) * 768 + kk;
    float4 a = *(const float4*)src, b = *(const float4*)(src + 4);
    union { uint16_t u[8]; uint4 v; } o;
    o.u[0] = f2bf(a.x); o.u[1] = f2bf(a.y); o.u[2] = f2bf(a.z); o.u[3] = f2bf(a.w);
    o.u[4] = f2bf(b.x); o.u[5] = f2bf(b.y); o.u[6] = f2bf(b.z); o.u[7] = f2bf(b.w);
    ((uint4*)Wob_pk)[i] = o.v;
  }
  if (i < 768) { bqkv[i] = bq[i]; bqkv[i + 768] = bk[i]; bqkv[i + 1536] = bv[i]; }
}

// ---------------- QKV GEMM with fused fp32->bf16 A conversion ----------------
// C[M,N] = tokens[M,768](fp32) * B[N,768]^T + bias. 128x128 tile, BK=64.
// A staged: fp32 chunks -> VGPR (coalesced 256B/8-lane group) -> f2bf -> ds_write_b128
// into the swizzled layout. B fragment-packed, direct to VGPR (R9-verified).
__global__ __launch_bounds__(256) void k_gemm_qkv(
    const float* __restrict__ Afp, const uint16_t* __restrict__ Bpk,
    const float* __restrict__ bias, uint16_t* __restrict__ C, int ldc, int ncol) {
  __shared__ uint16_t Alds[128 * 64];   // 16 KB
  const int tid  = threadIdx.x;
  const int w    = tid >> 6, lane = tid & 63;
  const int l32  = lane & 31, kh = lane >> 5;
  const int sup  = blockIdx.x / (32 * ncol);
  const int t    = blockIdx.x % (32 * ncol);
  const int row0 = (sup * 32 + (t & 31)) * 128, col0 = (t >> 5) * 128;
  const int wrow = (w >> 1) * 64,   wcol = (w & 1) * 64;

  const uint16_t* bw = Bpk + (size_t)((col0 >> 5) + (w & 1) * 2) * GS + lane * 8;

  // per-thread A chunk descriptors (4 chunks)
  int cr[4], cc4[4];
#pragma unroll
  for (int j = 0; j < 4; ++j) {
    int cid = j * 256 + w * 64 + lane;
    cr[j] = cid >> 3; cc4[j] = cid & 7;
  }

  f32x16 acc[2][2] = {};
  for (int kb = 0; kb < NKB; ++kb) {
    // B fragments: 8 contiguous-per-wave 16B loads (L2 hits)
    bf16x8 bfr[4][2];
#pragma unroll
    for (int ks = 0; ks < 4; ++ks)
#pragma unroll
      for (int nt = 0; nt < 2; ++nt)
        bfr[ks][nt] = *(const bf16x8*)(bw + (size_t)nt * GS + (kb * 4 + ks) * 512);
    // A fp32 chunks -> VGPRs (issue before barrier; no LDS dependence)
    float4 st[4][2];
#pragma unroll
    for (int j = 0; j < 4; ++j) {
      int c = cc4[j] ^ swz(cr[j]);
      const float* g = Afp + (size_t)(row0 + cr[j]) * 768 + kb * 64 + c * 8;
      st[j][0] = *(const float4*)g;
      st[j][1] = *(const float4*)(g + 4);
    }
    __syncthreads();                           // prev iter's A-frag reads done
#pragma unroll
    for (int j = 0; j < 4; ++j) {
      union { uint16_t u[8]; uint4 v; } o;
      o.u[0] = f2bf(st[j][0].x); o.u[1] = f2bf(st[j][0].y);
      o.u[2] = f2bf(st[j][0].z); o.u[3] = f2bf(st[j][0].w);
      o.u[4] = f2bf(st[j][1].x); o.u[5] = f2bf(st[j][1].y);
      o.u[6] = f2bf(st[j][1].z); o.u[7] = f2bf(st[j][1].w);
      *(uint4*)&Alds[cr[j] * 64 + cc4[j] * 8] = o.v;
    }
    __syncthreads();                           // staging visible
#pragma unroll
    for (int ks = 0; ks < 4; ++ks) {           // 4 k-steps of 16
      bf16x8 af[2];
#pragma unroll
      for (int mt = 0; mt < 2; ++mt) {
        int r = wrow + mt * 32 + l32;
        int c = (ks * 2 + kh) ^ swz(r);
        af[mt] = *(const bf16x8*)&Alds[r * 64 + c * 8];
      }
#pragma unroll
      for (int mt = 0; mt < 2; ++mt)
#pragma unroll
        for (int nt = 0; nt < 2; ++nt)
          acc[mt][nt] = MFMA32(af[mt], bfr[ks][nt], acc[mt][nt]);
    }
  }
  // epilogue: 32x32 C/D layout: col=lane&31, row=(reg&3)+8*(reg>>2)+4*(lane>>5)
#pragma unroll
  for (int nt = 0; nt < 2; ++nt) {
    int col = col0 + wcol + nt * 32 + l32;
    float bv = bias[col];
#pragma unroll
    for (int mt = 0; mt < 2; ++mt) {
#pragma unroll
      for (int rg = 0; rg < 16; ++rg) {
        int row = row0 + wrow + mt * 32 + (rg & 3) + 8 * (rg >> 2) + 4 * kh;
        C[(size_t)row * ldc + col] = f2bf(acc[mt][nt][rg] + bv);
      }
    }
  }
}

// ---------------- GEMM (bf16 A row-major staged via global_load_lds; packed B) ----------------
// R9 structure — used for the O-projection. K=768 fixed.
__global__ __launch_bounds__(256) void k_gemm_bt(
    const uint16_t* __restrict__ A, const uint16_t* __restrict__ Bpk,
    const float* __restrict__ bias, const float* __restrict__ rowscale,
    uint16_t* __restrict__ C, int ldc, int ncol) {
  __shared__ uint16_t Alds[128 * 64];   // 16 KB
  const int tid  = threadIdx.x;
  const int w    = tid >> 6, lane = tid & 63;
  const int wu   = __builtin_amdgcn_readfirstlane(w);
  const int l32  = lane & 31, kh = lane >> 5;
  const int sup  = blockIdx.x / (32 * ncol);
  const int t    = blockIdx.x % (32 * ncol);
  const int row0 = (sup * 32 + (t & 31)) * 128, col0 = (t >> 5) * 128;
  const int wrow = (w >> 1) * 64,   wcol = (w & 1) * 64;

  const uint16_t* bw = Bpk + (size_t)((col0 >> 5) + (w & 1) * 2) * GS + lane * 8;

  f32x16 acc[2][2] = {};
  for (int kb = 0; kb < NKB; ++kb) {
    bf16x8 bfr[4][2];
#pragma unroll
    for (int ks = 0; ks < 4; ++ks)
#pragma unroll
      for (int nt = 0; nt < 2; ++nt)
        bfr[ks][nt] = *(const bf16x8*)(bw + (size_t)nt * GS + (kb * 4 + ks) * 512);
    __syncthreads();
#pragma unroll
    for (int j = 0; j < 4; ++j) {                 // A: 1024 chunks
      int cid = j * 256 + w * 64 + lane;
      int r = cid >> 3, cc = cid & 7, c = cc ^ swz(r);
      async16(&Alds[(j * 256 + wu * 64) * 8],
              A + (size_t)(row0 + r) * 768 + kb * 64 + c * 8);
    }
    __syncthreads();
#pragma unroll
    for (int ks = 0; ks < 4; ++ks) {
      bf16x8 af[2];
#pragma unroll
      for (int mt = 0; mt < 2; ++mt) {
        int r = wrow + mt * 32 + l32;
        int c = (ks * 2 + kh) ^ swz(r);
        af[mt] = *(const bf16x8*)&Alds[r * 64 + c * 8];
      }
#pragma unroll
      for (int mt = 0; mt < 2; ++mt)
#pragma unroll
        for (int nt = 0; nt < 2; ++nt)
          acc[mt][nt] = MFMA32(af[mt], bfr[ks][nt], acc[mt][nt]);
    }
  }
#pragma unroll
  for (int nt = 0; nt < 2; ++nt) {
    int col = col0 + wcol + nt * 32 + l32;
    float bv = bias[col];
#pragma unroll
    for (int mt = 0; mt < 2; ++mt) {
#pragma unroll
      for (int rg = 0; rg < 16; ++rg) {
        int row = row0 + wrow + mt * 32 + (rg & 3) + 8 * (rg >> 2) + 4 * kh;
        float v = acc[mt][nt][rg] + bv;
        if (rowscale) v *= rowscale[row];
        C[(size_t)row * ldc + col] = f2bf(v);
      }
    }
  }
}

// ---------------- fused attention (R9 version; row-major output) ----------------
__global__ __launch_bounds__(256) void k_attn(
    const uint16_t* __restrict__ QKV, const float* __restrict__ ts,
    const float* __restrict__ mask, uint16_t* __restrict__ Aout) {
  __shared__ uint16_t Klds[64 * 64];        // swizzled chunks, 8KB
  __shared__ uint16_t Vt[64 * 72];          // [d][k] padded, 9KB
  __shared__ uint16_t Plds[4][32 * 72];     // per-wave P tile, stride 72, 18KB
  __shared__ float tkl[SEQ];                // ts*c2, masked -> +3e38

  const int tid = threadIdx.x, w = tid >> 6, lane = tid & 63;
  const int wu = __builtin_amdgcn_readfirstlane(w);
  const int quad = lane >> 4, l16 = lane & 15;
  int b = blockIdx.x;
  int xcd = b & 7, i = b >> 3;
  int qt = i & 3;
  int hg = xcd * 96 + (i >> 2);             // 0..767
  int n = hg / NH, h = hg % NH;
  const int q0 = qt * 128 + w * 32;
  const size_t rowbase = (size_t)n * SEQ * NQKV;

  const float c1 = 0.125f * 1.44269504f;     // scale * log2(e)
  const float c2 = 1.44269504f / 300.0f;     // log2(e) / tau

  for (int l = tid; l < SEQ; l += 256) {
    float t = ts[n * SEQ + l] * c2;
    tkl[l] = (mask[n * SEQ + l] > 0.f) ? t : 3e38f;
  }

  bf16x8 qf[2][2];
  float tq[2][4];
#pragma unroll
  for (int qs = 0; qs < 2; ++qs) {
    int qr = q0 + qs * 16 + l16;
    const uint16_t* qp = QKV + rowbase + (size_t)qr * NQKV + h * DH;
#pragma unroll
    for (int dsp = 0; dsp < 2; ++dsp)
      qf[qs][dsp] = *(const bf16x8*)(qp + dsp * 32 + quad * 8);
#pragma unroll
    for (int rg = 0; rg < 4; ++rg)
      tq[qs][rg] = ts[n * SEQ + q0 + qs * 16 + quad * 4 + rg] * c2;
  }

  f32x4 accO[2][4] = {};
  f32x4 accL[2] = {};
  bf16x8 ones_b;
  {
    union { uint16_t u[8]; bf16x8 v; } t;
    uint16_t o = (l16 == 0) ? 0x3F80 : 0;   // bf16 1.0 in column 0 only
#pragma unroll
    for (int j = 0; j < 8; ++j) t.u[j] = o;
    ones_b = t.v;
  }
  uint16_t* Pw = &Plds[w][0];

  for (int k0 = 0; k0 < SEQ; k0 += 64) {
    __syncthreads();
#pragma unroll
    for (int j = 0; j < 2; ++j) {
      int cid = j * 256 + w * 64 + lane;      // 0..511
      int r = cid >> 3, cc = cid & 7, c = cc ^ swz(r);
      const uint16_t* g = QKV + rowbase + (size_t)(k0 + r) * NQKV + DM + h * DH + c * 8;
      async16(&Klds[(j * 256 + wu * 64) * 8], g);
    }
    {
      int r = tid & 63, db = (tid >> 6) * 16;
      const uint16_t* g = QKV + rowbase + (size_t)(k0 + r) * NQKV + 2 * DM + h * DH + db;
      union { uint4 v; uint16_t u[8]; } a0, a1;
      a0.v = *(const uint4*)g;
      a1.v = *(const uint4*)(g + 8);
#pragma unroll
      for (int j = 0; j < 8; ++j) Vt[(db + j) * 72 + r] = a0.u[j];
#pragma unroll
      for (int j = 0; j < 8; ++j) Vt[(db + 8 + j) * 72 + r] = a1.u[j];
    }
    __syncthreads();

#pragma unroll
    for (int kt = 0; kt < 2; ++kt) {
      f32x4 s[2][2] = {};
#pragma unroll
      for (int dsp = 0; dsp < 2; ++dsp) {
        bf16x8 kf[2];
#pragma unroll
        for (int ksu = 0; ksu < 2; ++ksu) {
          int r = kt * 32 + 2 * l16 + ksu;
          int c = (dsp * 4 + quad) ^ swz(r);
          kf[ksu] = *(const bf16x8*)&Klds[r * 64 + c * 8];
        }
#pragma unroll
        for (int qs = 0; qs < 2; ++qs)
#pragma unroll
          for (int ksu = 0; ksu < 2; ++ksu)
            s[qs][ksu] = MFMA16(qf[qs][dsp], kf[ksu], s[qs][ksu]);
      }
      float tk0 = tkl[k0 + kt * 32 + 2 * l16];
      float tk1 = tkl[k0 + kt * 32 + 2 * l16 + 1];
#pragma unroll
      for (int qs = 0; qs < 2; ++qs) {
#pragma unroll
        for (int rg = 0; rg < 4; ++rg) {
          float d0 = fabsf(tq[qs][rg] - tk0);
          float d1 = fabsf(tq[qs][rg] - tk1);
          float p0 = __builtin_amdgcn_exp2f(fmaf(s[qs][0][rg], c1, -d0));
          float p1 = __builtin_amdgcn_exp2f(fmaf(s[qs][1][rg], c1, -d1));
          uint32_t u = (__float_as_uint(p0) >> 16) | (__float_as_uint(p1) & 0xFFFF0000u);
          *(uint32_t*)(Pw + (qs * 16 + quad * 4 + rg) * 72 + kt * 32 + 2 * l16) = u;
        }
      }
      bf16x8 vb[4];
#pragma unroll
      for (int dt = 0; dt < 4; ++dt)
        vb[dt] = *(const bf16x8*)&Vt[(dt * 16 + l16) * 72 + kt * 32 + quad * 8];
#pragma unroll
      for (int qs = 0; qs < 2; ++qs) {
        bf16x8 pa = *(const bf16x8*)(Pw + (qs * 16 + l16) * 72 + kt * 32 + quad * 8);
#pragma unroll
        for (int dt = 0; dt < 4; ++dt)
          accO[qs][dt] = MFMA16(pa, vb[dt], accO[qs][dt]);
        accL[qs] = MFMA16(pa, ones_b, accL[qs]);
      }
    }
  }
#pragma unroll
  for (int qs = 0; qs < 2; ++qs) {
    float inv[4];
#pragma unroll
    for (int rg = 0; rg < 4; ++rg) {
      float lv = __shfl(accL[qs][rg], lane & 48, 64);
      inv[rg] = 1.0f / lv;
    }
#pragma unroll
    for (int dt = 0; dt < 4; ++dt) {
#pragma unroll
      for (int rg = 0; rg < 4; ++rg) {
        int qr = q0 + qs * 16 + quad * 4 + rg;
        float v = accO[qs][dt][rg] * inv[rg];
        Aout[(size_t)(n * SEQ + qr) * DM + h * DH + dt * 16 + l16] = f2bf(v);
      }
    }
  }
}

// ---------------- readout pooling ----------------
__global__ __launch_bounds__(256) void k_pool(
    const uint16_t* __restrict__ Out, const float* __restrict__ mask,
    const float* __restrict__ readout, float* __restrict__ dst) {
  __shared__ float rsl[64];
  __shared__ float ex[SEQ];
  __shared__ float red[4];
  __shared__ float part[8][64];
  int b = blockIdx.x;
  int n = b / NH, h = b % NH;
  int tid = threadIdx.x;
  if (tid < 64) rsl[tid] = readout[h * DH + tid];
  __syncthreads();

  float suml = 0.f;
  for (int l = tid; l < SEQ; l += 256) {
    const uint16_t* rowp = Out + (size_t)(n * SEQ + l) * DM + h * DH;
    float acc = 0.f;
#pragma unroll
    for (int c = 0; c < 8; ++c) {
      union { uint4 v; uint16_t u[8]; } t;
      t.v = *(const uint4*)(rowp + c * 8);
#pragma unroll
      for (int j = 0; j < 8; ++j)
        acc += __uint_as_float(((uint32_t)t.u[j]) << 16) * rsl[c * 8 + j];
    }
    float e = __builtin_amdgcn_exp2f(acc * (0.125f * 1.44269504f));
    e = (mask[n * SEQ + l] > 0.f) ? e : 0.f;
    ex[l] = e;
    suml += e;
  }
#pragma unroll
  for (int off = 32; off; off >>= 1) suml += __shfl_down(suml, off, 64);
  if ((tid & 63) == 0) red[tid >> 6] = suml;
  __syncthreads();
  float inv = 1.0f / (red[0] + red[1] + red[2] + red[3]);

  int d0 = (tid & 31) * 2, ch = tid >> 5;
  float a0 = 0.f, a1 = 0.f;
  for (int l = ch * 64; l < ch * 64 + 64; ++l) {
    uint32_t pv = *(const uint32_t*)(Out + (size_t)(n * SEQ + l) * DM + h * DH + d0);
    float e = ex[l];
    a0 = fmaf(__uint_as_float(pv << 16), e, a0);
    a1 = fmaf(__uint_as_float(pv & 0xFFFF0000u), e, a1);
  }
  part[ch][d0] = a0;
  part[ch][d0 + 1] = a1;
  __syncthreads();
  if (tid < 64) {
    float s = 0.f;
#pragma unroll
    for (int c = 0; c < 8; ++c) s += part[c][tid];
    dst[n * DM + h * DH + tid] = s * inv;
  }
}

// ---------------- launch ----------------
extern "C" void kernel_launch(void* const* d_in, const int* in_sizes, int n_in,
                              void* d_out, int out_size, void* d_ws, size_t ws_size,
                              hipStream_t stream) {
  const float* tokens  = (const float*)d_in[0];
  const float* ts      = (const float*)d_in[1];
  const float* mask    = (const float*)d_in[2];
  const float* Wq      = (const float*)d_in[3];
  const float* bq      = (const float*)d_in[4];
  const float* Wk      = (const float*)d_in[5];
  const float* bk      = (const float*)d_in[6];
  const float* Wv      = (const float*)d_in[7];
  const float* bv      = (const float*)d_in[8];
  const float* Wo      = (const float*)d_in[9];
  const float* bo      = (const float*)d_in[10];
  const float* readout = (const float*)d_in[11];

  char* ws = (char*)d_ws;
  uint16_t* Aout = (uint16_t*)ws;                   // 50,331,648 B : attention output (row-major)
  uint16_t* Wqkv = (uint16_t*)(ws + 50331648);      //  3,538,944 B (packed)
  uint16_t* Wob  = (uint16_t*)(ws + 53870592);      //  1,179,648 B (packed)
  float*    bqkv = (float*)   (ws + 55050240);      //      9,216 B
  uint16_t* QKV  = (uint16_t*)(ws + 55059456);      // 150,994,944 B (row-major); reused as Out
  uint16_t* Outb = QKV;

  k_cvt<<<864, 256, 0, stream>>>(Wq, Wk, Wv, Wo, bq, bk, bv, Wqkv, Wob, bqkv);
  k_gemm_qkv<<<4608, 256, 0, stream>>>(tokens, Wqkv, bqkv, QKV, NQKV, 18);
  k_attn<<<3072, 256, 0, stream>>>(QKV, ts, mask, Aout);
  k_gemm_bt<<<1536, 256, 0, stream>>>(Aout, Wob, bo, mask, Outb, DM, 6);
  k_pool<<<768, 256, 0, stream>>>(Outb, mask, readout, (float*)d_out);
}